// Round 11
// baseline (248.265 us; speedup 1.0000x reference)
//
#include <hip/hip_runtime.h>
#include <hip/hip_bf16.h>
#include <math.h>

#define DIM 384
#define HEADS 6
#define DH 64
#define HIDDEN 1536
#define SEQ 2048
#define NTOK 8192          // B * SEQ
#define LN_EPS 1e-5f
#define S2PI 0.7978845608028654f
#define KPAD 72            // attention LDS rows: 144B (16B-aligned, 9 units... 8 used)

typedef __attribute__((ext_vector_type(8))) short short8;
typedef __attribute__((ext_vector_type(4))) float f32x4;
typedef __attribute__((ext_vector_type(4))) unsigned short ushort4v;
typedef __attribute__((ext_vector_type(8))) unsigned short ushort8v;

#if __has_builtin(__builtin_amdgcn_exp2f)
#define EXP2(x) __builtin_amdgcn_exp2f(x)
#else
#define EXP2(x) exp2f(x)
#endif
#if __has_builtin(__builtin_amdgcn_rcpf)
#define RCPF(x) __builtin_amdgcn_rcpf(x)
#else
#define RCPF(x) (1.f / (x))
#endif

__device__ __forceinline__ unsigned short f2bf(float f) {
    union { float f; unsigned u; } v; v.f = f;
    unsigned r = v.u + 0x7FFFu + ((v.u >> 16) & 1u);   // RNE
    return (unsigned short)(r >> 16);
}

__device__ __forceinline__ float bf2f(unsigned short u) {
    union { unsigned u; float f; } v; v.u = ((unsigned)u) << 16;
    return v.f;
}

// fast tanh-gelu: gelu = v*(1 - rcp(1+exp2(2*log2e*u)))
__device__ __forceinline__ float gelu_fast(float v) {
    float u = S2PI * (v + 0.044715f * v * v * v);
    float e = EXP2(u * 2.8853900817779268f);   // 2*log2(e)
    return v * (1.f - RCPF(1.f + e));
}

// 16B-unit XOR swizzle within a row (units 0..7 of the first 128B): T2 adapted.
__device__ __forceinline__ int swz(int row, int unit) { return unit ^ (row & 7); }

// async global->LDS, 16B per lane. LDS dest is wave-uniform base + lane*16.
__device__ __forceinline__ void gload16(const unsigned short* g, unsigned short* l) {
    __builtin_amdgcn_global_load_lds(
        (const __attribute__((address_space(1))) unsigned int*)g,
        (__attribute__((address_space(3))) unsigned int*)l, 16, 0, 0);
}

// ---------------- LN body: one wave per row of 384; f32 in -> bf16 out ----------
__device__ __forceinline__ void ln_body(const float* __restrict__ x,
                                        const float* __restrict__ g,
                                        const float* __restrict__ b,
                                        unsigned short* __restrict__ out,
                                        int blk, int tid) {
    int row  = blk * 4 + (tid >> 6);
    int lane = tid & 63;
    const float* xr = x + (size_t)row * DIM;
    float v[6];
    float s = 0.f, sq = 0.f;
#pragma unroll
    for (int j = 0; j < 6; ++j) {
        v[j] = xr[lane + 64 * j];
        s += v[j];
        sq += v[j] * v[j];
    }
#pragma unroll
    for (int o = 32; o; o >>= 1) {
        s  += __shfl_xor(s, o);
        sq += __shfl_xor(sq, o);
    }
    float mean = s * (1.f / DIM);
    float var  = sq * (1.f / DIM) - mean * mean;
    float rs   = rsqrtf(var + LN_EPS);
    unsigned short* orow = out + (size_t)row * DIM;
#pragma unroll
    for (int j = 0; j < 6; ++j) {
        int c = lane + 64 * j;
        orow[c] = f2bf((v[j] - mean) * rs * g[c] + b[c]);
    }
}

// ---------------- transpose body: w[K][N] f32 -> wt[N][K] bf16, 32x32 tile ------
__device__ __forceinline__ void tr_body(const float* __restrict__ w,
                                        unsigned short* __restrict__ wt,
                                        int K, int N, int bx, int by,
                                        unsigned short (*t)[36], int tid) {
    const int n0 = bx * 32, k0 = by * 32;
    {
        int r = tid >> 3, c4 = (tid & 7) * 4;
        float4 v = *reinterpret_cast<const float4*>(&w[(size_t)(k0 + r) * N + n0 + c4]);
        t[c4 + 0][r] = f2bf(v.x);
        t[c4 + 1][r] = f2bf(v.y);
        t[c4 + 2][r] = f2bf(v.z);
        t[c4 + 3][r] = f2bf(v.w);
    }
    __syncthreads();
    {
        int n = tid >> 3, kk = (tid & 7) * 4;
        ushort4v o = { t[n][kk], t[n][kk + 1], t[n][kk + 2], t[n][kk + 3] };
        *reinterpret_cast<ushort4v*>(&wt[(size_t)(n0 + n) * K + k0 + kk]) = o;
    }
}

// ---------------- fused prep: LN1 + all 4 weight transposes (1 dispatch) --------
__global__ __launch_bounds__(256) void prep_kernel(const float* __restrict__ x,
                                                   const float* __restrict__ g1,
                                                   const float* __restrict__ b1,
                                                   unsigned short* __restrict__ h_bf,
                                                   const float* __restrict__ w_qkv,
                                                   unsigned short* __restrict__ wqkv_t,
                                                   const float* __restrict__ w_proj,
                                                   unsigned short* __restrict__ wproj_t,
                                                   const float* __restrict__ w_fc1,
                                                   unsigned short* __restrict__ wfc1_t,
                                                   const float* __restrict__ w_fc2,
                                                   unsigned short* __restrict__ wfc2_t) {
    __shared__ unsigned short t[32][36];
    const int tid = threadIdx.x;
    int bid = blockIdx.x;
    if (bid < 2048) { ln_body(x, g1, b1, h_bf, bid, tid); return; }
    bid -= 2048;
    if (bid < 432) { tr_body(w_qkv, wqkv_t, DIM, 3 * DIM, bid % 36, bid / 36, t, tid); return; }
    bid -= 432;
    if (bid < 144) { tr_body(w_proj, wproj_t, DIM, DIM, bid % 12, bid / 12, t, tid); return; }
    bid -= 144;
    if (bid < 576) { tr_body(w_fc1, wfc1_t, DIM, HIDDEN, bid % 48, bid / 48, t, tid); return; }
    bid -= 576;
    tr_body(w_fc2, wfc2_t, HIDDEN, DIM, bid % 12, bid / 12, t, tid);
}

// ---------------- standalone LN (for LN2) ---------------------------------------
__global__ __launch_bounds__(256) void ln_kernel(const float* __restrict__ x,
                                                 const float* __restrict__ g,
                                                 const float* __restrict__ b,
                                                 unsigned short* __restrict__ out) {
    ln_body(x, g, b, out, blockIdx.x, threadIdx.x);
}

// ---------------- bf16 MFMA GEMM: C[M,N] = A[M,K] @ wt[N,K]^T -------------------
// 128xBN tile, 4 waves (2x2), BK=64, gload_lds staging.
// R11: LDS DOUBLE-BUFFER, ONE barrier per K-step. __syncthreads() drains vmcnt
// (tile t landed), then tile t+1's loads are issued into the other buffer and
// hide under tile t's MFMAs. WAR-safe: buf[cur] is rewritten only at step t+2,
// which is past the t+1 barrier; all reads of buf[cur] completed before it.
template <int EPI, int BN>
__global__ __launch_bounds__(256) void mfma_gemm(const unsigned short* __restrict__ A,
                                                 const unsigned short* __restrict__ Bt,
                                                 const float* __restrict__ bias,
                                                 const float* __restrict__ resid,
                                                 float* __restrict__ Cf,
                                                 unsigned short* __restrict__ Cb,
                                                 unsigned short* __restrict__ Qh,
                                                 unsigned short* __restrict__ Kh,
                                                 unsigned short* __restrict__ Vth,
                                                 int M, int N, int K) {
    constexpr int NF = BN / 32;
    constexpr int BUFSZ = 128 * 64 + BN * 64;   // shorts per buffer
    __shared__ __align__(16) unsigned short smem[2 * BUFSZ];  // EPI0(BN=128): 64KB >= T tile 34.8KB

    const int tid = threadIdx.x;
    const int wave = tid >> 6, lane = tid & 63;
    const int lg = lane >> 4, lrr = lane & 15;
    const int wr = wave >> 1, wc = wave & 1;
    const int bm = blockIdx.y * 128, bn = blockIdx.x * BN;

    f32x4 acc[4][NF];
    const f32x4 fzero = {0.f, 0.f, 0.f, 0.f};
#pragma unroll
    for (int m = 0; m < 4; ++m)
#pragma unroll
        for (int n = 0; n < NF; ++n) acc[m][n] = fzero;

    const int grow = wave * 8 + (lane >> 3);
    const int gcol = (lane & 7) * 8;
    const unsigned short* apl = A  + (size_t)(bm + grow) * K + gcol;
    const unsigned short* bpl = Bt + (size_t)(bn + grow) * K + gcol;

    const int nsteps = K / 64;
    {   // prologue: issue tile 0 into buffer 0
        unsigned short* As0 = smem;
        unsigned short* Bs0 = smem + 128 * 64;
#pragma unroll
        for (int i = 0; i < 4; ++i)
            gload16(apl + (size_t)(i * 32) * K, As0 + i * 2048 + wave * 512);
#pragma unroll
        for (int i = 0; i < NF; ++i)
            gload16(bpl + (size_t)(i * 32) * K, Bs0 + i * 2048 + wave * 512);
    }

    for (int t = 0; t < nsteps; ++t) {
        __syncthreads();   // drains vmcnt -> tile t staged; single barrier/step
        if (t + 1 < nsteps) {
            unsigned short* Asn = smem + ((t + 1) & 1) * BUFSZ;
            unsigned short* Bsn = Asn + 128 * 64;
            const int k1 = (t + 1) * 64;
#pragma unroll
            for (int i = 0; i < 4; ++i)
                gload16(apl + (size_t)(i * 32) * K + k1, Asn + i * 2048 + wave * 512);
#pragma unroll
            for (int i = 0; i < NF; ++i)
                gload16(bpl + (size_t)(i * 32) * K + k1, Bsn + i * 2048 + wave * 512);
        }
        const unsigned short* As = smem + (t & 1) * BUFSZ;
        const unsigned short* Bs = As + 128 * 64;
#pragma unroll
        for (int s = 0; s < 2; ++s) {
            short8 af[4], bf[NF];
#pragma unroll
            for (int m = 0; m < 4; ++m)
                af[m] = *reinterpret_cast<const short8*>(
                    &As[(wr * 64 + m * 16 + lrr) * 64 + s * 32 + lg * 8]);
#pragma unroll
            for (int n = 0; n < NF; ++n)
                bf[n] = *reinterpret_cast<const short8*>(
                    &Bs[(wc * (BN / 2) + n * 16 + lrr) * 64 + s * 32 + lg * 8]);
#pragma unroll
            for (int m = 0; m < 4; ++m)
#pragma unroll
                for (int n = 0; n < NF; ++n)
                    acc[m][n] = __builtin_amdgcn_mfma_f32_16x16x32_bf16(af[m], bf[n], acc[m][n], 0, 0, 0);
        }
    }

    if (EPI == 1) {
#pragma unroll
        for (int m = 0; m < 4; ++m)
#pragma unroll
            for (int j = 0; j < 4; ++j) {
                int row = bm + wr * 64 + m * 16 + lg * 4 + j;
#pragma unroll
                for (int n = 0; n < NF; ++n) {
                    int col = bn + wc * (BN / 2) + n * 16 + lrr;
                    size_t off = (size_t)row * N + col;
                    Cf[off] = acc[m][n][j] + bias[col] + resid[off];
                }
            }
    } else if (EPI == 2) {
#pragma unroll
        for (int m = 0; m < 4; ++m)
#pragma unroll
            for (int j = 0; j < 4; ++j) {
                int row = bm + wr * 64 + m * 16 + lg * 4 + j;
#pragma unroll
                for (int n = 0; n < NF; ++n) {
                    int col = bn + wc * (BN / 2) + n * 16 + lrr;
                    Cb[(size_t)row * N + col] = f2bf(gelu_fast(acc[m][n][j] + bias[col]));
                }
            }
    } else {
        const int sec = bn / DIM;   // 0=q 1=k 2=v
        if (sec < 2) {
            unsigned short* dst = (sec == 0) ? Qh : Kh;
#pragma unroll
            for (int m = 0; m < 4; ++m)
#pragma unroll
                for (int j = 0; j < 4; ++j) {
                    int token = bm + wr * 64 + m * 16 + lg * 4 + j;
                    int bb = token >> 11, nn = token & (SEQ - 1);
#pragma unroll
                    for (int n = 0; n < NF; ++n) {
                        int n_glob = bn + wc * (BN / 2) + n * 16 + lrr;
                        int head = (n_glob - sec * DIM) >> 6;
                        int d = n_glob & 63;
                        dst[((size_t)(bb * HEADS + head) * SEQ + nn) * DH + d] =
                            f2bf(acc[m][n][j]);
                    }
                }
        } else {
            // V: transpose C-tile in LDS, then coalesced writes along tokens.
            __syncthreads();
            unsigned short* T = smem;             // [128][136]
#pragma unroll
            for (int m = 0; m < 4; ++m)
#pragma unroll
                for (int n = 0; n < NF; ++n) {
                    int dl = wc * (BN / 2) + n * 16 + lrr;
#pragma unroll
                    for (int j = 0; j < 4; ++j) {
                        int tl = wr * 64 + m * 16 + lg * 4 + j;
                        T[dl * 136 + tl] = f2bf(acc[m][n][j]);
                    }
                }
            __syncthreads();
            int dl = tid >> 1, th = (tid & 1) * 64;
            int dg = bn - 2 * DIM + dl;
            int head = dg >> 6, dd = dg & 63;
            int bb = bm >> 11, nn0 = (bm & (SEQ - 1)) + th;
            unsigned short* dst = &Vth[((size_t)(bb * HEADS + head) * DH + dd) * SEQ + nn0];
#pragma unroll
            for (int i = 0; i < 64; i += 8)
                *reinterpret_cast<ushort8v*>(dst + i) =
                    *reinterpret_cast<const ushort8v*>(&T[dl * 136 + th + i]);
        }
    }
}

// ---------------- MFMA flash attention: swapped QK^T + T2 XOR-swizzled LDS ------
// All Ks/Vs/Ps accesses swizzle their 16B unit index with (row&7): kills the
// 8-way bank-start collisions of the 144B-stride b128 fragment reads.
__global__ __launch_bounds__(256) void attn_mfma_kernel(const unsigned short* __restrict__ Qh,
                                                        const unsigned short* __restrict__ Kh,
                                                        const unsigned short* __restrict__ Vth,
                                                        unsigned short* __restrict__ out) {
    const int bid = blockIdx.x;
    const int orig = (bid & 7) * 96 + (bid >> 3);   // XCD swizzle (768 = 8*96)
    const int qt = orig & 31;
    const int bh = orig >> 5;
    const int b = bh / HEADS, h = bh % HEADS;
    const int tid = threadIdx.x;
    const int wave = tid >> 6, lane = tid & 63;
    const int lg = lane >> 4;
    const int lrr = lane & 15;

    __shared__ __align__(16) unsigned short Ks[64][KPAD];
    __shared__ __align__(16) unsigned short Vs[64][KPAD];
    __shared__ __align__(16) unsigned short Ps[4][16][KPAD];

    const size_t qkbase = (size_t)bh * SEQ * DH;
    const size_t vbase  = (size_t)bh * DH * SEQ;

    short8 qfrag[2];
    {
        const unsigned short* qp =
            Qh + qkbase + (size_t)(qt * 64 + wave * 16 + lrr) * DH + lg * 8;
        qfrag[0] = *(const short8*)qp;
        qfrag[1] = *(const short8*)(qp + 32);
        // fold softmax scale * log2(e): P = exp2(S)
#pragma unroll
        for (int s = 0; s < 2; ++s)
#pragma unroll
            for (int i = 0; i < 8; ++i)
                qfrag[s][i] = (short)f2bf(bf2f((unsigned short)qfrag[s][i]) * 0.18033688011112042f);
    }

    float lsum = 0.f;
    f32x4 oacc[4];
    const f32x4 fzero = {0.f, 0.f, 0.f, 0.f};
#pragma unroll
    for (int n = 0; n < 4; ++n) oacc[n] = fzero;

    const int sr = tid >> 2;            // staging row 0..63
    const int u0 = (tid & 3) * 2;       // 16B units 0,2,4,6 (+1)

    // prologue: load tile 0 into regs (global cols match units u0, u0+1)
    const unsigned short* kp = Kh + qkbase + (size_t)sr * DH + u0 * 8;
    const unsigned short* vp = Vth + vbase + (size_t)sr * SEQ + u0 * 8;
    short8 rk0 = *(const short8*)kp;
    short8 rk1 = *(const short8*)(kp + 8);
    short8 rv0 = *(const short8*)vp;
    short8 rv1 = *(const short8*)(vp + 8);

    const int NT = SEQ / 64;
    for (int kt = 0; kt < NT; ++kt) {
        *(short8*)&Ks[sr][swz(sr, u0) * 8]     = rk0;
        *(short8*)&Ks[sr][swz(sr, u0 + 1) * 8] = rk1;
        *(short8*)&Vs[sr][swz(sr, u0) * 8]     = rv0;
        *(short8*)&Vs[sr][swz(sr, u0 + 1) * 8] = rv1;
        if (kt + 1 < NT) {          // async prefetch: lands under compute
            kp += 64 * DH;
            vp += 64;
            rk0 = *(const short8*)kp;
            rk1 = *(const short8*)(kp + 8);
            rv0 = *(const short8*)vp;
            rv1 = *(const short8*)(vp + 8);
        }
        asm volatile("s_waitcnt lgkmcnt(0)" ::: "memory");
        __builtin_amdgcn_s_barrier();
        __builtin_amdgcn_sched_barrier(0);

        // S^T = K @ Q^T (swapped): D[k][qrow]
        f32x4 sacc[4];
#pragma unroll
        for (int ct = 0; ct < 4; ++ct) sacc[ct] = fzero;
        __builtin_amdgcn_s_setprio(1);
#pragma unroll
        for (int ct = 0; ct < 4; ++ct) {
#pragma unroll
            for (int s = 0; s < 2; ++s) {
                short8 kf = *(const short8*)&Ks[ct * 16 + lrr][swz(lrr, s * 4 + lg) * 8];
                sacc[ct] = __builtin_amdgcn_mfma_f32_16x16x32_bf16(kf, qfrag[s], sacc[ct], 0, 0, 0);
            }
        }
        __builtin_amdgcn_s_setprio(0);

        // P = exp2(S); lane-local sum; pack 4 consecutive k as 2x bf16x2 -> b64.
#pragma unroll
        for (int ct = 0; ct < 4; ++ct) {
            float p0 = EXP2(sacc[ct][0]);
            float p1 = EXP2(sacc[ct][1]);
            float p2 = EXP2(sacc[ct][2]);
            float p3 = EXP2(sacc[ct][3]);
            lsum += (p0 + p1) + (p2 + p3);
            union { __hip_bfloat162 h2; unsigned u; } w0, w1;
            w0.h2 = __float22bfloat162_rn(float2{p0, p1});
            w1.h2 = __float22bfloat162_rn(float2{p2, p3});
            unsigned long long dw = (unsigned long long)w0.u |
                                    ((unsigned long long)w1.u << 32);
            // logical 8B quad at unit (ct*2 | lg>>1), inner offset (lg&1)*4 shorts
            int uq = (ct << 1) | (lg >> 1);
            *reinterpret_cast<unsigned long long*>(
                &Ps[wave][lrr][swz(lrr, uq) * 8 + (lg & 1) * 4]) = dw;
        }

        short8 pf0 = *(const short8*)&Ps[wave][lrr][swz(lrr, lg) * 8];
        short8 pf1 = *(const short8*)&Ps[wave][lrr][swz(lrr, 4 + lg) * 8];
        __builtin_amdgcn_s_setprio(1);
#pragma unroll
        for (int n = 0; n < 4; ++n) {
            short8 vf0 = *(const short8*)&Vs[n * 16 + lrr][swz(lrr, lg) * 8];
            oacc[n] = __builtin_amdgcn_mfma_f32_16x16x32_bf16(pf0, vf0, oacc[n], 0, 0, 0);
            short8 vf1 = *(const short8*)&Vs[n * 16 + lrr][swz(lrr, 4 + lg) * 8];
            oacc[n] = __builtin_amdgcn_mfma_f32_16x16x32_bf16(pf1, vf1, oacc[n], 0, 0, 0);
        }
        __builtin_amdgcn_s_setprio(0);
        __builtin_amdgcn_s_barrier();
    }

    // row-sum: lanes sharing lrr hold disjoint k-partials -> reduce across lg.
    float ls = lsum;
    ls += __shfl_xor(ls, 16);
    ls += __shfl_xor(ls, 32);
    float linv = 1.f / ls;          // lane r (r<16) now has 1/l for q-row r

    const int orow0 = qt * 64 + wave * 16 + lg * 4;
#pragma unroll
    for (int j = 0; j < 4; ++j) {
        float inv = __shfl(linv, lg * 4 + j);
        size_t rowoff = ((size_t)b * SEQ + orow0 + j) * DIM + h * DH + lrr;
#pragma unroll
        for (int n = 0; n < 4; ++n)
            out[rowoff + n * 16] = f2bf(oacc[n][j] * inv);
    }
}

// -------------------------------------------------------------------------------
extern "C" void kernel_launch(void* const* d_in, const int* in_sizes, int n_in,
                              void* d_out, int out_size, void* d_ws, size_t ws_size,
                              hipStream_t stream) {
    const float* x      = (const float*)d_in[0];
    const float* ln1_g  = (const float*)d_in[1];
    const float* ln1_b  = (const float*)d_in[2];
    const float* w_qkv  = (const float*)d_in[3];
    const float* w_proj = (const float*)d_in[4];
    const float* b_proj = (const float*)d_in[5];
    const float* ln2_g  = (const float*)d_in[6];
    const float* ln2_b  = (const float*)d_in[7];
    const float* w_fc1  = (const float*)d_in[8];
    const float* b_fc1  = (const float*)d_in[9];
    const float* w_fc2  = (const float*)d_in[10];
    const float* b_fc2  = (const float*)d_in[11];
    float* out = (float*)d_out;

    unsigned short* h_bf   = (unsigned short*)d_ws;
    unsigned short* Qh     = h_bf + (size_t)NTOK * DIM;
    unsigned short* Kh     = Qh + (size_t)NTOK * DIM;
    unsigned short* Vth    = Kh + (size_t)NTOK * DIM;
    unsigned short* fc1_bf = Vth + (size_t)NTOK * DIM;
    unsigned short* wqkv_t = fc1_bf + (size_t)NTOK * HIDDEN;
    unsigned short* wproj_t = wqkv_t + (size_t)DIM * 3 * DIM;
    unsigned short* wfc1_t  = wproj_t + (size_t)DIM * DIM;
    unsigned short* wfc2_t  = wfc1_t + (size_t)DIM * HIDDEN;
    unsigned short* attn_bf = h_bf;   // h dead after QKV gemm
    unsigned short* h2_bf   = Qh;     // Qh dead after attention

    // 0+1. fused prep: LN1 + all 4 weight transposes
    prep_kernel<<<3776, 256, 0, stream>>>(x, ln1_g, ln1_b, h_bf,
                                          w_qkv, wqkv_t, w_proj, wproj_t,
                                          w_fc1, wfc1_t, w_fc2, wfc2_t);

    // 2. QKV gemm -> Qh/Kh/Vth
    mfma_gemm<0, 128><<<dim3(3 * DIM / 128, NTOK / 128), 256, 0, stream>>>(
        h_bf, wqkv_t, nullptr, nullptr, nullptr, nullptr, Qh, Kh, Vth,
        NTOK, 3 * DIM, DIM);

    // 3. attention -> attn_bf  (1D grid, XCD-swizzled)
    attn_mfma_kernel<<<(SEQ / 64) * 4 * HEADS, 256, 0, stream>>>(
        Qh, Kh, Vth, attn_bf);

    // 4. out = x + attn_bf @ w_proj + b_proj   (f32; BN=64 -> 384 blocks)
    mfma_gemm<1, 64><<<dim3(DIM / 64, NTOK / 128), 256, 0, stream>>>(
        attn_bf, wproj_t, b_proj, x, out, nullptr, nullptr, nullptr, nullptr,
        NTOK, DIM, DIM);

    // 5. h2 = LN2(out)  (bf16)
    ln_kernel<<<NTOK / 4, 256, 0, stream>>>(out, ln2_g, ln2_b, h2_bf);

    // 6. fc1 = gelu(h2 @ w_fc1 + b_fc1)  (bf16, fast gelu)
    mfma_gemm<2, 128><<<dim3(HIDDEN / 128, NTOK / 128), 256, 0, stream>>>(
        h2_bf, wfc1_t, b_fc1, nullptr, nullptr, fc1_bf, nullptr, nullptr, nullptr,
        NTOK, HIDDEN, DIM);

    // 7. out = out + fc1 @ w_fc2 + b_fc2  (f32; BN=64 -> 384 blocks)
    mfma_gemm<1, 64><<<dim3(DIM / 64, NTOK / 128), 256, 0, stream>>>(
        fc1_bf, wfc2_t, b_fc2, out, out, nullptr, nullptr, nullptr, nullptr,
        NTOK, DIM, HIDDEN);
}

// Round 12
// 229.826 us; speedup vs baseline: 1.0802x; 1.0802x over previous
//
#include <hip/hip_runtime.h>
#include <hip/hip_bf16.h>
#include <math.h>

#define DIM 384
#define HEADS 6
#define DH 64
#define HIDDEN 1536
#define SEQ 2048
#define NTOK 8192          // B * SEQ
#define LN_EPS 1e-5f
#define S2PI 0.7978845608028654f
#define KPAD 72            // attention LDS rows: 144B stride = 36 dwords -> rotates
                           // bank-start by 4/row; fragment reads land conflict-free
                           // in-order. DO NOT add XOR swizzle on top (R11: 3.5x
                           // conflicts -- parity collapse onto even bank groups).

typedef __attribute__((ext_vector_type(8))) short short8;
typedef __attribute__((ext_vector_type(4))) float f32x4;
typedef __attribute__((ext_vector_type(4))) unsigned short ushort4v;
typedef __attribute__((ext_vector_type(8))) unsigned short ushort8v;

#if __has_builtin(__builtin_amdgcn_exp2f)
#define EXP2(x) __builtin_amdgcn_exp2f(x)
#else
#define EXP2(x) exp2f(x)
#endif
#if __has_builtin(__builtin_amdgcn_rcpf)
#define RCPF(x) __builtin_amdgcn_rcpf(x)
#else
#define RCPF(x) (1.f / (x))
#endif

__device__ __forceinline__ unsigned short f2bf(float f) {
    union { float f; unsigned u; } v; v.f = f;
    unsigned r = v.u + 0x7FFFu + ((v.u >> 16) & 1u);   // RNE
    return (unsigned short)(r >> 16);
}

__device__ __forceinline__ float bf2f(unsigned short u) {
    union { unsigned u; float f; } v; v.u = ((unsigned)u) << 16;
    return v.f;
}

// fast tanh-gelu: gelu = v*(1 - rcp(1+exp2(2*log2e*u)))
__device__ __forceinline__ float gelu_fast(float v) {
    float u = S2PI * (v + 0.044715f * v * v * v);
    float e = EXP2(u * 2.8853900817779268f);   // 2*log2(e)
    return v * (1.f - RCPF(1.f + e));
}

// async global->LDS, 16B per lane. LDS dest is wave-uniform base + lane*16.
__device__ __forceinline__ void gload16(const unsigned short* g, unsigned short* l) {
    __builtin_amdgcn_global_load_lds(
        (const __attribute__((address_space(1))) unsigned int*)g,
        (__attribute__((address_space(3))) unsigned int*)l, 16, 0, 0);
}

// ---------------- LN body: one wave per row of 384; f32 in -> bf16 out ----------
__device__ __forceinline__ void ln_body(const float* __restrict__ x,
                                        const float* __restrict__ g,
                                        const float* __restrict__ b,
                                        unsigned short* __restrict__ out,
                                        int blk, int tid) {
    int row  = blk * 4 + (tid >> 6);
    int lane = tid & 63;
    const float* xr = x + (size_t)row * DIM;
    float v[6];
    float s = 0.f, sq = 0.f;
#pragma unroll
    for (int j = 0; j < 6; ++j) {
        v[j] = xr[lane + 64 * j];
        s += v[j];
        sq += v[j] * v[j];
    }
#pragma unroll
    for (int o = 32; o; o >>= 1) {
        s  += __shfl_xor(s, o);
        sq += __shfl_xor(sq, o);
    }
    float mean = s * (1.f / DIM);
    float var  = sq * (1.f / DIM) - mean * mean;
    float rs   = rsqrtf(var + LN_EPS);
    unsigned short* orow = out + (size_t)row * DIM;
#pragma unroll
    for (int j = 0; j < 6; ++j) {
        int c = lane + 64 * j;
        orow[c] = f2bf((v[j] - mean) * rs * g[c] + b[c]);
    }
}

// ---------------- transpose body: w[K][N] f32 -> wt[N][K] bf16, 32x32 tile ------
__device__ __forceinline__ void tr_body(const float* __restrict__ w,
                                        unsigned short* __restrict__ wt,
                                        int K, int N, int bx, int by,
                                        unsigned short (*t)[36], int tid) {
    const int n0 = bx * 32, k0 = by * 32;
    {
        int r = tid >> 3, c4 = (tid & 7) * 4;
        float4 v = *reinterpret_cast<const float4*>(&w[(size_t)(k0 + r) * N + n0 + c4]);
        t[c4 + 0][r] = f2bf(v.x);
        t[c4 + 1][r] = f2bf(v.y);
        t[c4 + 2][r] = f2bf(v.z);
        t[c4 + 3][r] = f2bf(v.w);
    }
    __syncthreads();
    {
        int n = tid >> 3, kk = (tid & 7) * 4;
        ushort4v o = { t[n][kk], t[n][kk + 1], t[n][kk + 2], t[n][kk + 3] };
        *reinterpret_cast<ushort4v*>(&wt[(size_t)(n0 + n) * K + k0 + kk]) = o;
    }
}

// ---------------- fused prep: LN1 + all 4 weight transposes (1 dispatch) --------
__global__ __launch_bounds__(256) void prep_kernel(const float* __restrict__ x,
                                                   const float* __restrict__ g1,
                                                   const float* __restrict__ b1,
                                                   unsigned short* __restrict__ h_bf,
                                                   const float* __restrict__ w_qkv,
                                                   unsigned short* __restrict__ wqkv_t,
                                                   const float* __restrict__ w_proj,
                                                   unsigned short* __restrict__ wproj_t,
                                                   const float* __restrict__ w_fc1,
                                                   unsigned short* __restrict__ wfc1_t,
                                                   const float* __restrict__ w_fc2,
                                                   unsigned short* __restrict__ wfc2_t) {
    __shared__ unsigned short t[32][36];
    const int tid = threadIdx.x;
    int bid = blockIdx.x;
    if (bid < 2048) { ln_body(x, g1, b1, h_bf, bid, tid); return; }
    bid -= 2048;
    if (bid < 432) { tr_body(w_qkv, wqkv_t, DIM, 3 * DIM, bid % 36, bid / 36, t, tid); return; }
    bid -= 432;
    if (bid < 144) { tr_body(w_proj, wproj_t, DIM, DIM, bid % 12, bid / 12, t, tid); return; }
    bid -= 144;
    if (bid < 576) { tr_body(w_fc1, wfc1_t, DIM, HIDDEN, bid % 48, bid / 48, t, tid); return; }
    bid -= 576;
    tr_body(w_fc2, wfc2_t, HIDDEN, DIM, bid % 12, bid / 12, t, tid);
}

// ---------------- standalone LN (for LN2) ---------------------------------------
__global__ __launch_bounds__(256) void ln_kernel(const float* __restrict__ x,
                                                 const float* __restrict__ g,
                                                 const float* __restrict__ b,
                                                 unsigned short* __restrict__ out) {
    ln_body(x, g, b, out, blockIdx.x, threadIdx.x);
}

// ---------------- bf16 MFMA GEMM: C[M,N] = A[M,K] @ wt[N,K]^T -------------------
// 128xBN tile, 4 waves (2x2), BK=64, gload_lds staging.
// LDS DOUBLE-BUFFER, ONE barrier per K-step (R11-validated: rest -15us).
template <int EPI, int BN>
__global__ __launch_bounds__(256) void mfma_gemm(const unsigned short* __restrict__ A,
                                                 const unsigned short* __restrict__ Bt,
                                                 const float* __restrict__ bias,
                                                 const float* __restrict__ resid,
                                                 float* __restrict__ Cf,
                                                 unsigned short* __restrict__ Cb,
                                                 unsigned short* __restrict__ Qh,
                                                 unsigned short* __restrict__ Kh,
                                                 unsigned short* __restrict__ Vth,
                                                 int M, int N, int K) {
    constexpr int NF = BN / 32;
    constexpr int BUFSZ = 128 * 64 + BN * 64;   // shorts per buffer
    __shared__ __align__(16) unsigned short smem[2 * BUFSZ];

    const int tid = threadIdx.x;
    const int wave = tid >> 6, lane = tid & 63;
    const int lg = lane >> 4, lrr = lane & 15;
    const int wr = wave >> 1, wc = wave & 1;
    const int bm = blockIdx.y * 128, bn = blockIdx.x * BN;

    f32x4 acc[4][NF];
    const f32x4 fzero = {0.f, 0.f, 0.f, 0.f};
#pragma unroll
    for (int m = 0; m < 4; ++m)
#pragma unroll
        for (int n = 0; n < NF; ++n) acc[m][n] = fzero;

    const int grow = wave * 8 + (lane >> 3);
    const int gcol = (lane & 7) * 8;
    const unsigned short* apl = A  + (size_t)(bm + grow) * K + gcol;
    const unsigned short* bpl = Bt + (size_t)(bn + grow) * K + gcol;

    const int nsteps = K / 64;
    {   // prologue: issue tile 0 into buffer 0
        unsigned short* As0 = smem;
        unsigned short* Bs0 = smem + 128 * 64;
#pragma unroll
        for (int i = 0; i < 4; ++i)
            gload16(apl + (size_t)(i * 32) * K, As0 + i * 2048 + wave * 512);
#pragma unroll
        for (int i = 0; i < NF; ++i)
            gload16(bpl + (size_t)(i * 32) * K, Bs0 + i * 2048 + wave * 512);
    }

    for (int t = 0; t < nsteps; ++t) {
        __syncthreads();   // drains vmcnt -> tile t staged; single barrier/step
        if (t + 1 < nsteps) {
            unsigned short* Asn = smem + ((t + 1) & 1) * BUFSZ;
            unsigned short* Bsn = Asn + 128 * 64;
            const int k1 = (t + 1) * 64;
#pragma unroll
            for (int i = 0; i < 4; ++i)
                gload16(apl + (size_t)(i * 32) * K + k1, Asn + i * 2048 + wave * 512);
#pragma unroll
            for (int i = 0; i < NF; ++i)
                gload16(bpl + (size_t)(i * 32) * K + k1, Bsn + i * 2048 + wave * 512);
        }
        const unsigned short* As = smem + (t & 1) * BUFSZ;
        const unsigned short* Bs = As + 128 * 64;
#pragma unroll
        for (int s = 0; s < 2; ++s) {
            short8 af[4], bf[NF];
#pragma unroll
            for (int m = 0; m < 4; ++m)
                af[m] = *reinterpret_cast<const short8*>(
                    &As[(wr * 64 + m * 16 + lrr) * 64 + s * 32 + lg * 8]);
#pragma unroll
            for (int n = 0; n < NF; ++n)
                bf[n] = *reinterpret_cast<const short8*>(
                    &Bs[(wc * (BN / 2) + n * 16 + lrr) * 64 + s * 32 + lg * 8]);
#pragma unroll
            for (int m = 0; m < 4; ++m)
#pragma unroll
                for (int n = 0; n < NF; ++n)
                    acc[m][n] = __builtin_amdgcn_mfma_f32_16x16x32_bf16(af[m], bf[n], acc[m][n], 0, 0, 0);
        }
    }

    if (EPI == 1) {
#pragma unroll
        for (int m = 0; m < 4; ++m)
#pragma unroll
            for (int j = 0; j < 4; ++j) {
                int row = bm + wr * 64 + m * 16 + lg * 4 + j;
#pragma unroll
                for (int n = 0; n < NF; ++n) {
                    int col = bn + wc * (BN / 2) + n * 16 + lrr;
                    size_t off = (size_t)row * N + col;
                    Cf[off] = acc[m][n][j] + bias[col] + resid[off];
                }
            }
    } else if (EPI == 2) {
#pragma unroll
        for (int m = 0; m < 4; ++m)
#pragma unroll
            for (int j = 0; j < 4; ++j) {
                int row = bm + wr * 64 + m * 16 + lg * 4 + j;
#pragma unroll
                for (int n = 0; n < NF; ++n) {
                    int col = bn + wc * (BN / 2) + n * 16 + lrr;
                    Cb[(size_t)row * N + col] = f2bf(gelu_fast(acc[m][n][j] + bias[col]));
                }
            }
    } else {
        const int sec = bn / DIM;   // 0=q 1=k 2=v
        if (sec < 2) {
            unsigned short* dst = (sec == 0) ? Qh : Kh;
#pragma unroll
            for (int m = 0; m < 4; ++m)
#pragma unroll
                for (int j = 0; j < 4; ++j) {
                    int token = bm + wr * 64 + m * 16 + lg * 4 + j;
                    int bb = token >> 11, nn = token & (SEQ - 1);
#pragma unroll
                    for (int n = 0; n < NF; ++n) {
                        int n_glob = bn + wc * (BN / 2) + n * 16 + lrr;
                        int head = (n_glob - sec * DIM) >> 6;
                        int d = n_glob & 63;
                        dst[((size_t)(bb * HEADS + head) * SEQ + nn) * DH + d] =
                            f2bf(acc[m][n][j]);
                    }
                }
        } else {
            // V: transpose C-tile in LDS, then coalesced writes along tokens.
            __syncthreads();
            unsigned short* T = smem;             // [128][136]
#pragma unroll
            for (int m = 0; m < 4; ++m)
#pragma unroll
                for (int n = 0; n < NF; ++n) {
                    int dl = wc * (BN / 2) + n * 16 + lrr;
#pragma unroll
                    for (int j = 0; j < 4; ++j) {
                        int tl = wr * 64 + m * 16 + lg * 4 + j;
                        T[dl * 136 + tl] = f2bf(acc[m][n][j]);
                    }
                }
            __syncthreads();
            int dl = tid >> 1, th = (tid & 1) * 64;
            int dg = bn - 2 * DIM + dl;
            int head = dg >> 6, dd = dg & 63;
            int bb = bm >> 11, nn0 = (bm & (SEQ - 1)) + th;
            unsigned short* dst = &Vth[((size_t)(bb * HEADS + head) * DH + dd) * SEQ + nn0];
#pragma unroll
            for (int i = 0; i < 64; i += 8)
                *reinterpret_cast<ushort8v*>(dst + i) =
                    *reinterpret_cast<const ushort8v*>(&T[dl * 136 + th + i]);
        }
    }
}

// ---------------- MFMA flash attention: swapped QK^T, no-max, K-SPLIT=2 ---------
// No-max softmax partials are ADDITIVE: O_p = sum exp(S)V, l_p = sum exp(S).
// 1536 blocks: part p handles K-tiles [p*16, p*16+16). Partial O (f32, no
// divide) -> Opart[p]; row-sums -> lpart[p]. combine_kernel merges.
// XCD swizzle: orig=(bid&7)*192+(bid>>3); each XCD sees 6 bh (3MB K/V, L2-fit).
__global__ __launch_bounds__(256) void attn_mfma_kernel(const unsigned short* __restrict__ Qh,
                                                        const unsigned short* __restrict__ Kh,
                                                        const unsigned short* __restrict__ Vth,
                                                        float* __restrict__ Opart,
                                                        float* __restrict__ lpart) {
    const int bid = blockIdx.x;
    const int orig = (bid & 7) * 192 + (bid >> 3);   // 1536 = 8 * 192
    int rem = orig;
    int part = 0;
    if (rem >= 768) { part = 1; rem -= 768; }
    const int qt = rem & 31;
    const int bh = rem >> 5;
    const int b = bh / HEADS, h = bh % HEADS;
    const int tid = threadIdx.x;
    const int wave = tid >> 6, lane = tid & 63;
    const int lg = lane >> 4;
    const int lrr = lane & 15;

    __shared__ __align__(16) unsigned short Ks[64][KPAD];
    __shared__ __align__(16) unsigned short Vs[64][KPAD];
    __shared__ __align__(16) unsigned short Ps[4][16][KPAD];

    const size_t qkbase = (size_t)bh * SEQ * DH;
    const size_t vbase  = (size_t)bh * DH * SEQ;

    short8 qfrag[2];
    {
        const unsigned short* qp =
            Qh + qkbase + (size_t)(qt * 64 + wave * 16 + lrr) * DH + lg * 8;
        qfrag[0] = *(const short8*)qp;
        qfrag[1] = *(const short8*)(qp + 32);
        // fold softmax scale * log2(e): P = exp2(S)
#pragma unroll
        for (int s = 0; s < 2; ++s)
#pragma unroll
            for (int i = 0; i < 8; ++i)
                qfrag[s][i] = (short)f2bf(bf2f((unsigned short)qfrag[s][i]) * 0.18033688011112042f);
    }

    float lsum = 0.f;
    f32x4 oacc[4];
    const f32x4 fzero = {0.f, 0.f, 0.f, 0.f};
#pragma unroll
    for (int n = 0; n < 4; ++n) oacc[n] = fzero;

    const int sr = tid >> 2;            // staging row 0..63
    const int sc = (tid & 3) * 16;      // staging col (shorts)

    // prologue: load this part's tile 0 into regs
    const int kt0 = part * 16;
    const unsigned short* kp = Kh + qkbase + (size_t)(kt0 * 64 + sr) * DH + sc;
    const unsigned short* vp = Vth + vbase + (size_t)sr * SEQ + kt0 * 64 + sc;
    short8 rk0 = *(const short8*)kp;
    short8 rk1 = *(const short8*)(kp + 8);
    short8 rv0 = *(const short8*)vp;
    short8 rv1 = *(const short8*)(vp + 8);

    const int NT = 16;                  // tiles per part
    for (int kt = 0; kt < NT; ++kt) {
        *(short8*)&Ks[sr][sc]     = rk0;
        *(short8*)&Ks[sr][sc + 8] = rk1;
        *(short8*)&Vs[sr][sc]     = rv0;
        *(short8*)&Vs[sr][sc + 8] = rv1;
        if (kt + 1 < NT) {          // async prefetch: lands under compute
            kp += 64 * DH;
            vp += 64;
            rk0 = *(const short8*)kp;
            rk1 = *(const short8*)(kp + 8);
            rv0 = *(const short8*)vp;
            rv1 = *(const short8*)(vp + 8);
        }
        asm volatile("s_waitcnt lgkmcnt(0)" ::: "memory");
        __builtin_amdgcn_s_barrier();
        __builtin_amdgcn_sched_barrier(0);

        // S^T = K @ Q^T (swapped): D[k][qrow]
        f32x4 sacc[4];
#pragma unroll
        for (int ct = 0; ct < 4; ++ct) sacc[ct] = fzero;
        __builtin_amdgcn_s_setprio(1);
#pragma unroll
        for (int ct = 0; ct < 4; ++ct) {
#pragma unroll
            for (int s = 0; s < 2; ++s) {
                short8 kf = *(const short8*)&Ks[ct * 16 + lrr][s * 32 + lg * 8];
                sacc[ct] = __builtin_amdgcn_mfma_f32_16x16x32_bf16(kf, qfrag[s], sacc[ct], 0, 0, 0);
            }
        }
        __builtin_amdgcn_s_setprio(0);

        // P = exp2(S); lane-local sum; pack 4 consecutive k as 2x bf16x2 -> b64.
#pragma unroll
        for (int ct = 0; ct < 4; ++ct) {
            float p0 = EXP2(sacc[ct][0]);
            float p1 = EXP2(sacc[ct][1]);
            float p2 = EXP2(sacc[ct][2]);
            float p3 = EXP2(sacc[ct][3]);
            lsum += (p0 + p1) + (p2 + p3);
            union { __hip_bfloat162 h2; unsigned u; } w0, w1;
            w0.h2 = __float22bfloat162_rn(float2{p0, p1});
            w1.h2 = __float22bfloat162_rn(float2{p2, p3});
            unsigned long long dw = (unsigned long long)w0.u |
                                    ((unsigned long long)w1.u << 32);
            *reinterpret_cast<unsigned long long*>(&Ps[wave][lrr][ct * 16 + lg * 4]) = dw;
        }

        short8 pf0 = *(const short8*)&Ps[wave][lrr][lg * 8];
        short8 pf1 = *(const short8*)&Ps[wave][lrr][32 + lg * 8];
        __builtin_amdgcn_s_setprio(1);
#pragma unroll
        for (int n = 0; n < 4; ++n) {
            short8 vf0 = *(const short8*)&Vs[n * 16 + lrr][lg * 8];
            oacc[n] = __builtin_amdgcn_mfma_f32_16x16x32_bf16(pf0, vf0, oacc[n], 0, 0, 0);
            short8 vf1 = *(const short8*)&Vs[n * 16 + lrr][32 + lg * 8];
            oacc[n] = __builtin_amdgcn_mfma_f32_16x16x32_bf16(pf1, vf1, oacc[n], 0, 0, 0);
        }
        __builtin_amdgcn_s_setprio(0);
        __builtin_amdgcn_s_barrier();
    }

    // row-sum for q-row lrr: reduce partials across lg (xor 16, 32).
    float ls = lsum;
    ls += __shfl_xor(ls, 16);
    ls += __shfl_xor(ls, 32);
    if (lane < 16)
        lpart[((size_t)part * 24 + bh) * SEQ + qt * 64 + wave * 16 + lane] = ls;

    float* Op = Opart + (size_t)part * NTOK * DIM;
    const int orow0 = qt * 64 + wave * 16 + lg * 4;
#pragma unroll
    for (int j = 0; j < 4; ++j) {
        size_t rowoff = ((size_t)b * SEQ + orow0 + j) * DIM + h * DH + lrr;
#pragma unroll
        for (int n = 0; n < 4; ++n)
            Op[rowoff + n * 16] = oacc[n][j];
    }
}

// ---------------- combine: out = (O0+O1)/(l0+l1) -> bf16 ------------------------
__global__ __launch_bounds__(256) void combine_kernel(const float* __restrict__ Opart,
                                                      const float* __restrict__ lpart,
                                                      unsigned short* __restrict__ outbf) {
    int row  = blockIdx.x * 4 + (threadIdx.x >> 6);
    int lane = threadIdx.x & 63;
    int b = row >> 11, n = row & (SEQ - 1);
    const float* O1 = Opart + (size_t)NTOK * DIM;
    size_t ro = (size_t)row * DIM;
#pragma unroll
    for (int j = 0; j < 6; ++j) {       // head h == j (c = lane + 64j, Dh = 64)
        size_t li = ((size_t)b * HEADS + j) * SEQ + n;
        float l = lpart[li] + lpart[(size_t)24 * SEQ + li];
        float inv = 1.f / l;
        size_t c = ro + lane + 64 * j;
        outbf[c] = f2bf((Opart[c] + O1[c]) * inv);
    }
}

// -------------------------------------------------------------------------------
extern "C" void kernel_launch(void* const* d_in, const int* in_sizes, int n_in,
                              void* d_out, int out_size, void* d_ws, size_t ws_size,
                              hipStream_t stream) {
    const float* x      = (const float*)d_in[0];
    const float* ln1_g  = (const float*)d_in[1];
    const float* ln1_b  = (const float*)d_in[2];
    const float* w_qkv  = (const float*)d_in[3];
    const float* w_proj = (const float*)d_in[4];
    const float* b_proj = (const float*)d_in[5];
    const float* ln2_g  = (const float*)d_in[6];
    const float* ln2_b  = (const float*)d_in[7];
    const float* w_fc1  = (const float*)d_in[8];
    const float* b_fc1  = (const float*)d_in[9];
    const float* w_fc2  = (const float*)d_in[10];
    const float* b_fc2  = (const float*)d_in[11];
    float* out = (float*)d_out;

    unsigned short* h_bf   = (unsigned short*)d_ws;
    unsigned short* Qh     = h_bf + (size_t)NTOK * DIM;
    unsigned short* Kh     = Qh + (size_t)NTOK * DIM;
    unsigned short* Vth    = Kh + (size_t)NTOK * DIM;
    unsigned short* fc1_bf = Vth + (size_t)NTOK * DIM;
    unsigned short* wqkv_t = fc1_bf + (size_t)NTOK * HIDDEN;
    unsigned short* wproj_t = wqkv_t + (size_t)DIM * 3 * DIM;
    unsigned short* wfc1_t  = wproj_t + (size_t)DIM * DIM;
    unsigned short* wfc2_t  = wfc1_t + (size_t)DIM * HIDDEN;
    float* lpart = (float*)(wfc2_t + (size_t)DIM * HIDDEN);   // 2*24*2048 f32
    unsigned short* attn_bf = h_bf;    // h dead after QKV gemm
    unsigned short* h2_bf   = Qh;      // Qh dead after attention+combine
    float* Opart = (float*)fc1_bf;     // 2*NTOK*DIM f32 == NTOK*HIDDEN bf16 bytes;
                                       // fc1_bf dead until FC1 gemm (after combine)

    // 0+1. fused prep: LN1 + all 4 weight transposes
    prep_kernel<<<3776, 256, 0, stream>>>(x, ln1_g, ln1_b, h_bf,
                                          w_qkv, wqkv_t, w_proj, wproj_t,
                                          w_fc1, wfc1_t, w_fc2, wfc2_t);

    // 2. QKV gemm -> Qh/Kh/Vth
    mfma_gemm<0, 128><<<dim3(3 * DIM / 128, NTOK / 128), 256, 0, stream>>>(
        h_bf, wqkv_t, nullptr, nullptr, nullptr, nullptr, Qh, Kh, Vth,
        NTOK, 3 * DIM, DIM);

    // 3a. attention partials (K-split=2, 1536 blocks, XCD-swizzled)
    attn_mfma_kernel<<<2 * (SEQ / 64) * 4 * HEADS, 256, 0, stream>>>(
        Qh, Kh, Vth, Opart, lpart);

    // 3b. combine partials -> attn_bf
    combine_kernel<<<NTOK / 4, 256, 0, stream>>>(Opart, lpart, attn_bf);

    // 4. out = x + attn_bf @ w_proj + b_proj   (f32; BN=64 -> 384 blocks)
    mfma_gemm<1, 64><<<dim3(DIM / 64, NTOK / 128), 256, 0, stream>>>(
        attn_bf, wproj_t, b_proj, x, out, nullptr, nullptr, nullptr, nullptr,
        NTOK, DIM, DIM);

    // 5. h2 = LN2(out)  (bf16)
    ln_kernel<<<NTOK / 4, 256, 0, stream>>>(out, ln2_g, ln2_b, h2_bf);

    // 6. fc1 = gelu(h2 @ w_fc1 + b_fc1)  (bf16, fast gelu; overwrites Opart)
    mfma_gemm<2, 128><<<dim3(HIDDEN / 128, NTOK / 128), 256, 0, stream>>>(
        h2_bf, wfc1_t, b_fc1, nullptr, nullptr, fc1_bf, nullptr, nullptr, nullptr,
        NTOK, HIDDEN, DIM);

    // 7. out = out + fc1 @ w_fc2 + b_fc2  (f32; BN=64 -> 384 blocks)
    mfma_gemm<1, 64><<<dim3(DIM / 64, NTOK / 128), 256, 0, stream>>>(
        fc1_bf, wfc2_t, b_fc2, out, out, nullptr, nullptr, nullptr, nullptr,
        NTOK, DIM, HIDDEN);
}